// Round 2
// baseline (737.854 us; speedup 1.0000x reference)
//
#include <hip/hip_runtime.h>

// Decoder layer, MI355X gfx950. GEMMs: bf16 MFMA 16x16x32, m97-style
// global_load_lds(16B) staging. Attention: split-KV x3, key-interleaved LDS
// (packed b64 P writes), constant-max exp2 softmax, fused Q-RoPE.
// R1: attn LDS XOR swizzle (conflicts 11.4M->4.8M).
// R2: T3 minimal double-buffer pipeline in attn_k / gemm_bf / gemm_gateup:
// prefetch next tile's global_load_lds BEFORE compute, ONE barrier per iter
// (vmcnt(0) drain lands after compute -> load latency hidden).
// Workspace: 88 MB, liveness-packed (see map in kernel_launch).

#define S_LEN   2048
#define D_MODEL 2048
#define NH      16
#define KVHEADS 8
#define HDIM    128
#define FFDIM   5632
#define PREFIX  2048
#define KVLEN   4096
#define SM_L2E  0.12751744f             // (1/sqrt(128)) * log2(e)
#define MCONST  16.0f                   // fixed softmax max (log2 domain)
#define LN10K_64 0.14391156831212787f   // ln(10000)/64

using bf16x8 = __attribute__((ext_vector_type(8))) short;
using f32x4  = __attribute__((ext_vector_type(4))) float;

__device__ __forceinline__ unsigned f2bf_u(float f) {
  unsigned u = __float_as_uint(f);
  return (u + 0x7fffu + ((u >> 16) & 1u)) >> 16;   // RNE
}
__device__ __forceinline__ unsigned short f2bf(float f) { return (unsigned short)f2bf_u(f); }
__device__ __forceinline__ float bf2f(unsigned short u) {
  return __uint_as_float((unsigned)u << 16);
}
__device__ __forceinline__ unsigned pack2(float a, float b) {
  return f2bf_u(a) | (f2bf_u(b) << 16);
}
__device__ __forceinline__ uint2 pack4(float4 v) {
  uint2 r;
  r.x = pack2(v.x, v.y);
  r.y = pack2(v.z, v.w);
  return r;
}
__device__ __forceinline__ f32x4 mfma16(bf16x8 a, bf16x8 b, f32x4 c) {
  return __builtin_amdgcn_mfma_f32_16x16x32_bf16(a, b, c, 0, 0, 0);
}
__device__ __forceinline__ void gl2lds16(const unsigned short* g, unsigned short* l) {
  __builtin_amdgcn_global_load_lds(
      (__attribute__((address_space(1))) void*)(unsigned short*)g,
      (__attribute__((address_space(3))) void*)l, 16, 0, 0);
}

// ---------------- fp32 -> bf16 weight conversion ----------------
__device__ __forceinline__ void conv_body(const float* __restrict__ src,
                                          unsigned short* __restrict__ dst,
                                          int bseg, int tid) {
  size_t i = (size_t)bseg * 256 + tid;
  const float4* s4 = (const float4*)src;
  float4 a = s4[2 * i], b = s4[2 * i + 1];
  uint2 lo = pack4(a), hi = pack4(b);
  ((uint4*)dst)[i] = make_uint4(lo.x, lo.y, hi.x, hi.y);
}
__global__ __launch_bounds__(256) void convw_k(const float* __restrict__ src,
                                               unsigned short* __restrict__ dst) {
  conv_body(src, dst, blockIdx.x, threadIdx.x);
}
// q (2048 blocks) + k (1024) + v (1024) -> fused WQKV
__global__ __launch_bounds__(256) void conv3_k(const float* __restrict__ q,
                                               const float* __restrict__ k,
                                               const float* __restrict__ v,
                                               unsigned short* __restrict__ dst) {
  int b = blockIdx.x;
  if (b < 2048)      conv_body(q, dst, b, threadIdx.x);
  else if (b < 3072) conv_body(k, dst + (size_t)2048 * 2048, b - 2048, threadIdx.x);
  else               conv_body(v, dst + (size_t)3072 * 2048, b - 3072, threadIdx.x);
}
// gate (5632) + up (5632)
__global__ __launch_bounds__(256) void conv2_k(const float* __restrict__ g,
                                               const float* __restrict__ u,
                                               unsigned short* __restrict__ wg,
                                               unsigned short* __restrict__ wu) {
  int b = blockIdx.x;
  if (b < 5632) conv_body(g, wg, b, threadIdx.x);
  else          conv_body(u, wu, b - 5632, threadIdx.x);
}

// ---------------- RMSNorm -> bf16 out; input fp32 or bf16 ----------------
template <bool INBF>
__global__ __launch_bounds__(256) void rmsnorm_k(const void* __restrict__ xin,
                                                 const float* __restrict__ w,
                                                 unsigned short* __restrict__ out) {
  const int row = blockIdx.x, tid = threadIdx.x;
  float v[8];
  if constexpr (INBF) {
    const unsigned short* xr = (const unsigned short*)xin + (size_t)row * D_MODEL;
    uint4 u = ((const uint4*)xr)[tid];
    v[0] = bf2f((unsigned short)(u.x & 0xffff)); v[1] = bf2f((unsigned short)(u.x >> 16));
    v[2] = bf2f((unsigned short)(u.y & 0xffff)); v[3] = bf2f((unsigned short)(u.y >> 16));
    v[4] = bf2f((unsigned short)(u.z & 0xffff)); v[5] = bf2f((unsigned short)(u.z >> 16));
    v[6] = bf2f((unsigned short)(u.w & 0xffff)); v[7] = bf2f((unsigned short)(u.w >> 16));
  } else {
    const float4* xr = (const float4*)((const float*)xin + (size_t)row * D_MODEL);
    float4 a = xr[2 * tid], b = xr[2 * tid + 1];
    v[0] = a.x; v[1] = a.y; v[2] = a.z; v[3] = a.w;
    v[4] = b.x; v[5] = b.y; v[6] = b.z; v[7] = b.w;
  }
  float ss = 0.f;
#pragma unroll
  for (int i = 0; i < 8; i++) ss += v[i] * v[i];
#pragma unroll
  for (int off = 1; off < 64; off <<= 1) ss += __shfl_xor(ss, off);
  __shared__ float red[4];
  if ((tid & 63) == 0) red[tid >> 6] = ss;
  __syncthreads();
  const float sc = rsqrtf((red[0] + red[1] + red[2] + red[3]) * (1.0f / D_MODEL) + 1e-5f);
  const float4* w4 = (const float4*)w;
  float4 wa = w4[2 * tid], wb = w4[2 * tid + 1];
  float4 oa = make_float4(v[0]*sc*wa.x, v[1]*sc*wa.y, v[2]*sc*wa.z, v[3]*sc*wa.w);
  float4 ob = make_float4(v[4]*sc*wb.x, v[5]*sc*wb.y, v[6]*sc*wb.z, v[7]*sc*wb.w);
  uint2 lo = pack4(oa), hi = pack4(ob);
  ((uint4*)(out + (size_t)row * D_MODEL))[tid] = make_uint4(lo.x, lo.y, hi.x, hi.y);
}

// ---------------- GEMM: C[M,N] = A[M,K](bf16) @ B[N,K](bf16)^T ----------------
// R2: double-buffered LDS, prefetch-next-then-compute, 1 barrier/iter.
template <int BN, int EPI>
__global__ __launch_bounds__(256) void gemm_bf(const unsigned short* __restrict__ A,
                                               const unsigned short* __restrict__ B,
                                               const void* __restrict__ res,
                                               void* __restrict__ C,
                                               int M, int N, int K) {
  constexpr int NI = BN / 32;
  constexpr int ASZ = 128 * 32, BSZ = BN * 32;
  __shared__ __align__(16) unsigned short lA[2 * ASZ];
  __shared__ __align__(16) unsigned short lB[2 * BSZ];
  const int tid = threadIdx.x, lane = tid & 63, wave = tid >> 6;
  const int r16 = lane & 15, q4 = lane >> 4;
  const int wm = wave >> 1, wn = wave & 1;
  const int m0 = blockIdx.x * 128, n0 = blockIdx.y * BN;

  const int lr = lane >> 2;
  const int lc = (lane & 3) * 8;
  const unsigned short* gA0 = A + (size_t)(m0 + wave * 16 + lr) * K + lc;
  const unsigned short* gA1 = A + (size_t)(m0 + 64 + wave * 16 + lr) * K + lc;
  unsigned short* lA0 = lA + (wave * 16) * 32;
  unsigned short* lA1 = lA + (64 + wave * 16) * 32;
  const unsigned short* gB0 = B + (size_t)(n0 + wave * 16 + lr) * K + lc;
  const unsigned short* gB1 = B + (size_t)(n0 + 64 + wave * 16 + lr) * K + lc;
  unsigned short* lB0 = lB + (wave * 16) * 32;
  unsigned short* lB1 = lB + (64 + wave * 16) * 32;

  f32x4 acc[4][NI];
#pragma unroll
  for (int i = 0; i < 4; i++)
#pragma unroll
    for (int j = 0; j < NI; j++) acc[i][j] = f32x4{0.f, 0.f, 0.f, 0.f};

  // prologue: stage k-tile 0 into buffer 0
  gl2lds16(gA0, lA0);
  gl2lds16(gA1, lA1);
  gl2lds16(gB0, lB0);
  if constexpr (BN == 128) gl2lds16(gB1, lB1);
  gA0 += 32; gA1 += 32; gB0 += 32;
  if constexpr (BN == 128) gB1 += 32;
  __syncthreads();

  int bs = 0;
  for (int k0 = 0; k0 < K; k0 += 32) {
    if (k0 + 32 < K) {      // prefetch next tile into the other buffer
      const int ao = (bs ^ 1) * ASZ, bo = (bs ^ 1) * BSZ;
      gl2lds16(gA0, lA0 + ao);
      gl2lds16(gA1, lA1 + ao);
      gl2lds16(gB0, lB0 + bo);
      if constexpr (BN == 128) gl2lds16(gB1, lB1 + bo);
      gA0 += 32; gA1 += 32; gB0 += 32;
      if constexpr (BN == 128) gB1 += 32;
    }
    const int ar = bs * ASZ, br = bs * BSZ;
    bf16x8 af[4], bfr[NI];
#pragma unroll
    for (int mi = 0; mi < 4; mi++)
      af[mi] = *(const bf16x8*)&lA[ar + (wm * 64 + mi * 16 + r16) * 32 + q4 * 8];
#pragma unroll
    for (int ni = 0; ni < NI; ni++)
      bfr[ni] = *(const bf16x8*)&lB[br + (wn * (BN / 2) + ni * 16 + r16) * 32 + q4 * 8];
#pragma unroll
    for (int mi = 0; mi < 4; mi++)
#pragma unroll
      for (int ni = 0; ni < NI; ni++)
        acc[mi][ni] = mfma16(af[mi], bfr[ni], acc[mi][ni]);
    __syncthreads();   // drains this wave's prefetch vmcnt; frees buf bs
    bs ^= 1;
  }
#pragma unroll
  for (int mi = 0; mi < 4; mi++)
#pragma unroll
    for (int ni = 0; ni < NI; ni++) {
      int col = n0 + wn * (BN / 2) + ni * 16 + r16;
#pragma unroll
      for (int rr = 0; rr < 4; rr++) {
        int row = m0 + wm * 64 + mi * 16 + q4 * 4 + rr;
        size_t idx = (size_t)row * N + col;
        float v = acc[mi][ni][rr];
        if constexpr (EPI == 0) {
          ((unsigned short*)C)[idx] = f2bf(v);
        } else if constexpr (EPI == 1) {
          ((unsigned short*)C)[idx] = f2bf(v + ((const float*)res)[idx]);
        } else {
          ((float*)C)[idx] = v + bf2f(((const unsigned short*)res)[idx]);
        }
      }
    }
}

// ---------------- Fused gate/up GEMM + silu*mul -> bf16 (BM=128, BN=64) ----------------
// R2: double-buffered, same pipeline as gemm_bf.
__global__ __launch_bounds__(256) void gemm_gateup(const unsigned short* __restrict__ A,
                                                   const unsigned short* __restrict__ Bg,
                                                   const unsigned short* __restrict__ Bu,
                                                   unsigned short* __restrict__ act) {
  constexpr int ASZ = 128 * 32, GSZ = 64 * 32;
  __shared__ __align__(16) unsigned short lA[2 * ASZ];
  __shared__ __align__(16) unsigned short lG[2 * GSZ];
  __shared__ __align__(16) unsigned short lU[2 * GSZ];
  const int tid = threadIdx.x, lane = tid & 63, wave = tid >> 6;
  const int r16 = lane & 15, q4 = lane >> 4;
  const int wm = wave >> 1, wn = wave & 1;
  const int m0 = blockIdx.x * 128, n0 = blockIdx.y * 64;
  const int K = D_MODEL;

  const int lr = lane >> 2, lc = (lane & 3) * 8;
  const unsigned short* gA0 = A + (size_t)(m0 + wave * 16 + lr) * K + lc;
  const unsigned short* gA1 = A + (size_t)(m0 + 64 + wave * 16 + lr) * K + lc;
  unsigned short* lA0 = lA + (wave * 16) * 32;
  unsigned short* lA1 = lA + (64 + wave * 16) * 32;
  const unsigned short* gG0 = Bg + (size_t)(n0 + wave * 16 + lr) * K + lc;
  const unsigned short* gU0 = Bu + (size_t)(n0 + wave * 16 + lr) * K + lc;
  unsigned short* lG0 = lG + (wave * 16) * 32;
  unsigned short* lU0 = lU + (wave * 16) * 32;

  f32x4 ag[4][2], au[4][2];
#pragma unroll
  for (int i = 0; i < 4; i++)
#pragma unroll
    for (int j = 0; j < 2; j++) { ag[i][j] = f32x4{0.f,0.f,0.f,0.f}; au[i][j] = f32x4{0.f,0.f,0.f,0.f}; }

  // prologue
  gl2lds16(gA0, lA0);
  gl2lds16(gA1, lA1);
  gl2lds16(gG0, lG0);
  gl2lds16(gU0, lU0);
  gA0 += 32; gA1 += 32; gG0 += 32; gU0 += 32;
  __syncthreads();

  int bs = 0;
  for (int k0 = 0; k0 < K; k0 += 32) {
    if (k0 + 32 < K) {
      const int ao = (bs ^ 1) * ASZ, go = (bs ^ 1) * GSZ;
      gl2lds16(gA0, lA0 + ao);
      gl2lds16(gA1, lA1 + ao);
      gl2lds16(gG0, lG0 + go);
      gl2lds16(gU0, lU0 + go);
      gA0 += 32; gA1 += 32; gG0 += 32; gU0 += 32;
    }
    const int ar = bs * ASZ, gr = bs * GSZ;
    bf16x8 af[4], bg2[2], bu2[2];
#pragma unroll
    for (int mi = 0; mi < 4; mi++)
      af[mi] = *(const bf16x8*)&lA[ar + (wm * 64 + mi * 16 + r16) * 32 + q4 * 8];
#pragma unroll
    for (int ni = 0; ni < 2; ni++) {
      int r = gr + (wn * 32 + ni * 16 + r16) * 32 + q4 * 8;
      bg2[ni] = *(const bf16x8*)&lG[r];
      bu2[ni] = *(const bf16x8*)&lU[r];
    }
#pragma unroll
    for (int mi = 0; mi < 4; mi++)
#pragma unroll
      for (int ni = 0; ni < 2; ni++) {
        ag[mi][ni] = mfma16(af[mi], bg2[ni], ag[mi][ni]);
        au[mi][ni] = mfma16(af[mi], bu2[ni], au[mi][ni]);
      }
    __syncthreads();
    bs ^= 1;
  }
#pragma unroll
  for (int mi = 0; mi < 4; mi++)
#pragma unroll
    for (int ni = 0; ni < 2; ni++) {
      int col = n0 + wn * 32 + ni * 16 + r16;
#pragma unroll
      for (int rr = 0; rr < 4; rr++) {
        int row = m0 + wm * 64 + mi * 16 + q4 * 4 + rr;
        float g = ag[mi][ni][rr], u = au[mi][ni][rr];
        float sil = g / (1.0f + __expf(-g));
        act[(size_t)row * FFDIM + col] = f2bf(sil * u);
      }
    }
}

// -------- RoPE for keys: fp32 cache + bf16 new (GQA repeat) -> keys_bf[H][KV][HD] --------
__global__ __launch_bounds__(256) void rope_k_k(const float* __restrict__ k_cache,
                                                const unsigned short* __restrict__ qkv,
                                                unsigned short* __restrict__ keys_bf) {
  int idx = blockIdx.x * 256 + threadIdx.x;        // [h][j][d]
  int d = idx & 127, j = (idx >> 7) & 4095, h = idx >> 19;
  int dd = d & 63;
  float inv = __expf(-(float)dd * LN10K_64);
  float ang = (float)j * inv;
  float c = cosf(ang), sn = sinf(ang);
  float x, xr;
  if (j < PREFIX) {
    const float* row = k_cache + ((size_t)h * PREFIX + j) * HDIM;
    x = row[d];
    xr = (d < 64) ? -row[d + 64] : row[d - 64];
  } else {
    const unsigned short* row = qkv + (size_t)(j - PREFIX) * 4096 + 2048 + (h >> 1) * HDIM;
    x = bf2f(row[d]);
    xr = (d < 64) ? -bf2f(row[d + 64]) : bf2f(row[d - 64]);
  }
  keys_bf[idx] = f2bf(x * c + xr * sn);
}

// -------- V transpose: fp32 cache + bf16 new -> vals_t[H][HD][KV] bf16 --------
__global__ __launch_bounds__(256) void vtrans_k(const float* __restrict__ v_cache,
                                                const unsigned short* __restrict__ qkv,
                                                unsigned short* __restrict__ vals_t) {
  __shared__ float tile[32][33];
  const int h = blockIdx.z, j0 = blockIdx.x * 32, d0 = blockIdx.y * 32;
  const int t = threadIdx.x;
#pragma unroll
  for (int i = 0; i < 4; i++) {
    int e = i * 256 + t;
    int jj = e >> 5, dd = e & 31;
    float v;
    if (j0 < PREFIX)
      v = v_cache[((size_t)h * PREFIX + j0 + jj) * HDIM + d0 + dd];
    else
      v = bf2f(qkv[(size_t)(j0 - PREFIX + jj) * 4096 + 3072 + (h >> 1) * HDIM + d0 + dd]);
    tile[jj][dd] = v;
  }
  __syncthreads();
#pragma unroll
  for (int i = 0; i < 4; i++) {
    int e = i * 256 + t;
    int dd = e >> 5, jj = e & 31;
    vals_t[((size_t)h * HDIM + d0 + dd) * KVLEN + j0 + jj] = f2bf(tile[jj][dd]);
  }
}

// ---------------- Split-KV flash attention v2 ----------------
// Grid (32 q-blocks, 16 heads, 3 segs). Key-interleaved K staging (LDS row
// rho holds key (rho&15)*4 + (rho>>4)) so each lane's 4 scores/row are 4
// consecutive keys -> one packed ds_write_b64 into lP. Constant-max exp2
// softmax (no running max / rescale). Q-RoPE fused at load.
// R1 LDS layouts (all XOR-swizzled, slot ^= row&7, 16B slots):
//   lK [2][64 rho][128 dims]  256B rows — pre-swizzled global source
//   lV [2][128 dim][64 keys]  128B rows — pre-swizzled global source
//   lP [wave][16 q][64 keys]  128B rows — swizzled ds_write_b64 / ds_read_b128
// R2: K/V double-buffered; prefetch tile t+1 before computing tile t;
// single barrier per tile. Prologue stage overlaps Q-RoPE VALU.
__global__ __launch_bounds__(256) void attn_k(const unsigned short* __restrict__ qkv,
                                              const unsigned short* __restrict__ keys,
                                              const unsigned short* __restrict__ valst,
                                              const int* __restrict__ chunkp,
                                              unsigned short* __restrict__ pO,
                                              float* __restrict__ pl) {
  constexpr int KSZ = 64 * 128;    // shorts per K buffer (16 KB)
  constexpr int VSZ = 128 * 64;    // shorts per V buffer (16 KB)
  __shared__ __align__(16) unsigned short lK[2 * KSZ];
  __shared__ __align__(16) unsigned short lV[2 * VSZ];
  __shared__ __align__(16) unsigned short lP[4][16 * 64];
  const int h = blockIdx.y, q0 = blockIdx.x * 64, seg = blockIdx.z;
  const int tid = threadIdx.x, wave = tid >> 6, lane = tid & 63;
  const int r16 = lane & 15, q4 = lane >> 4;
  const int chunk = chunkp[0];
  const int sw = (r16 & 7) << 4;                 // read-side XOR swizzle

  const unsigned short* Kh = keys + (size_t)h * KVLEN * HDIM;
  const unsigned short* Vh = valst + (size_t)h * HDIM * KVLEN;

  // ---- staging bases (linear LDS dest; XOR-swizzled global source) ----
  const int krow = wave * 4 + (lane >> 4);                       // rho & 15
  const unsigned short* kSrc = Kh + (size_t)(krow * 4) * HDIM
                               + (((lane & 15) ^ (krow & 7)) * 8);
  unsigned short* kDst = lK + (wave * 4) * 128;
  const int vrow = wave * 8 + (lane >> 3);
  const unsigned short* vSrc = Vh + (size_t)vrow * KVLEN
                               + (((lane & 7) ^ ((lane >> 3) & 7)) * 8);
  unsigned short* vDst = lV + (wave * 8) * 64;

  int kt0, ktN;
  if (seg == 0)      { kt0 = 0;    ktN = 1024; }
  else if (seg == 1) { kt0 = 1024; ktN = 2048; }
  else { int cs = (q0 / chunk) * chunk; kt0 = PREFIX + cs; ktN = PREFIX + q0 + 64; }

  // ---- prologue: stage first tile into buffer 0 (latency hides under RoPE) ----
#pragma unroll
  for (int i = 0; i < 4; i++)
    gl2lds16(kSrc + (size_t)(kt0 + i) * HDIM, kDst + i * 16 * 128);
#pragma unroll
  for (int i = 0; i < 4; i++)
    gl2lds16(vSrc + (size_t)i * 32 * KVLEN + kt0, vDst + i * 32 * 64);

  // ---- Q load + RoPE (A-frag row = q0+wave*16+r16, dims ks*32+q4*8..+7) ----
  const int qrow = q0 + wave * 16 + r16;
  const unsigned short* qr = qkv + (size_t)qrow * 4096 + h * HDIM;
  float qx[4][8];
#pragma unroll
  for (int ks = 0; ks < 4; ks++) {
    bf16x8 raw = *(const bf16x8*)(qr + ks * 32 + q4 * 8);
#pragma unroll
    for (int j = 0; j < 8; j++) qx[ks][j] = bf2f((unsigned short)raw[j]);
  }
  const float pos = (float)(PREFIX + qrow);
  bf16x8 qf[4];
#pragma unroll
  for (int ks = 0; ks < 4; ks++)
#pragma unroll
    for (int j = 0; j < 8; j++) {
      int d = ks * 32 + q4 * 8 + j;
      float inv = __expf(-(float)(d & 63) * LN10K_64);
      float ang = pos * inv;
      float c = cosf(ang), sn = sinf(ang);
      float other = qx[ks ^ 2][j];
      float rot = (ks < 2) ? -other : other;
      qf[ks][j] = (short)f2bf(qx[ks][j] * c + rot * sn);
    }

  float lrow[4] = {0.f, 0.f, 0.f, 0.f};
  f32x4 oacc[8];
#pragma unroll
  for (int ni = 0; ni < 8; ni++) oacc[ni] = f32x4{0.f, 0.f, 0.f, 0.f};

  const int irow_base = q0 + wave * 16 + q4 * 4;   // C-layout rows

  __syncthreads();                                 // first tile ready

  int bs = 0;
  for (int kt = kt0; kt < ktN; kt += 64) {
    // prefetch next tile into the other buffer (freed by last iter's barrier)
    if (kt + 64 < ktN) {
      const int ko = (bs ^ 1) * KSZ, vo = (bs ^ 1) * VSZ;
#pragma unroll
      for (int i = 0; i < 4; i++)
        gl2lds16(kSrc + (size_t)(kt + 64 + i) * HDIM, kDst + ko + i * 16 * 128);
#pragma unroll
      for (int i = 0; i < 4; i++)
        gl2lds16(vSrc + (size_t)i * 32 * KVLEN + kt + 64, vDst + vo + i * 32 * 64);
    }
    const bool domask = (seg == 2) && (kt - PREFIX + 64 > q0);
    const char* lKc = (const char*)lK + bs * (KSZ * 2);   // byte offset
    const char* lVc = (const char*)lV + bs * (VSZ * 2);
    // QK — kf row j*16+r16 (256B rows), dim bytes (ks*64+q4*16)^sw
    f32x4 s[4];
#pragma unroll
    for (int j = 0; j < 4; j++) s[j] = f32x4{0.f, 0.f, 0.f, 0.f};
#pragma unroll
    for (int ks = 0; ks < 4; ks++)
#pragma unroll
      for (int j = 0; j < 4; j++) {
        bf16x8 kf = *(const bf16x8*)(lKc + (j * 16 + r16) * 256
                                     + ((ks * 64 + q4 * 16) ^ sw));
        s[j] = mfma16(qf[ks], kf, s[j]);
      }
    // constant-max softmax; lane's cols = keys kt + r16*4 + j
    const int klb = kt - PREFIX + r16 * 4;
#pragma unroll
    for (int rr = 0; rr < 4; rr++) {
      float e0 = fmaf(s[0][rr], SM_L2E, -MCONST);
      float e1 = fmaf(s[1][rr], SM_L2E, -MCONST);
      float e2 = fmaf(s[2][rr], SM_L2E, -MCONST);
      float e3 = fmaf(s[3][rr], SM_L2E, -MCONST);
      if (domask) {
        int irow = irow_base + rr;
        if (klb     > irow) e0 = -1e30f;
        if (klb + 1 > irow) e1 = -1e30f;
        if (klb + 2 > irow) e2 = -1e30f;
        if (klb + 3 > irow) e3 = -1e30f;
      }
      float p0 = exp2f(e0), p1 = exp2f(e1), p2 = exp2f(e2), p3 = exp2f(e3);
      lrow[rr] += (p0 + p1) + (p2 + p3);
      uint2 pk = make_uint2(pack2(p0, p1), pack2(p2, p3));
      int qrw = q4 * 4 + rr;                         // q-row within 16-tile
      *(uint2*)((char*)lP[wave] + qrw * 128 + ((r16 * 8) ^ ((qrw & 7) << 4))) = pk;
    }
    // PV (P exchange is intra-wave; DS ops are in-order per wave)
    bf16x8 pf0 = *(const bf16x8*)((const char*)lP[wave] + r16 * 128
                                  + ((q4 * 16) ^ sw));
    bf16x8 pf1 = *(const bf16x8*)((const char*)lP[wave] + r16 * 128
                                  + ((64 + q4 * 16) ^ sw));
#pragma unroll
    for (int ni = 0; ni < 8; ni++) {
      bf16x8 v0 = *(const bf16x8*)(lVc + (ni * 16 + r16) * 128
                                   + ((q4 * 16) ^ sw));
      oacc[ni] = mfma16(pf0, v0, oacc[ni]);
      bf16x8 v1 = *(const bf16x8*)(lVc + (ni * 16 + r16) * 128
                                   + ((64 + q4 * 16) ^ sw));
      oacc[ni] = mfma16(pf1, v1, oacc[ni]);
    }
    __syncthreads();   // drains prefetch vmcnt; frees buf bs for next prefetch
    bs ^= 1;
  }

  // deferred cross-lane l reduction (over the 16 r16 lanes)
#pragma unroll
  for (int rr = 0; rr < 4; rr++) {
    lrow[rr] += __shfl_xor(lrow[rr], 1);
    lrow[rr] += __shfl_xor(lrow[rr], 2);
    lrow[rr] += __shfl_xor(lrow[rr], 4);
    lrow[rr] += __shfl_xor(lrow[rr], 8);
  }
  const size_t base = (size_t)(seg * NH + h) * S_LEN;
#pragma unroll
  for (int ni = 0; ni < 8; ni++)
#pragma unroll
    for (int rr = 0; rr < 4; rr++)
      pO[(base + irow_base + rr) * HDIM + ni * 16 + r16] = f2bf(oacc[ni][rr]);
  if (r16 == 0) {
#pragma unroll
    for (int rr = 0; rr < 4; rr++) pl[base + irow_base + rr] = lrow[rr];
  }
}

// ---------------- combine 3 split-KV partials (same const max) ----------------
__global__ __launch_bounds__(256) void attn_combine(const unsigned short* __restrict__ pO,
                                                    const float* __restrict__ pl,
                                                    unsigned short* __restrict__ out) {
  int idx = blockIdx.x * 256 + threadIdx.x;        // [h][q][d]
  int d = idx & 127, hq = idx >> 7;                // hq = h*2048+q
  const int R = NH * S_LEN;
  float L = pl[hq] + pl[hq + R] + pl[hq + 2 * R];
  float o = bf2f(pO[(size_t)hq * HDIM + d])
          + bf2f(pO[(size_t)(hq + R) * HDIM + d])
          + bf2f(pO[(size_t)(hq + 2 * R) * HDIM + d]);
  int h = hq >> 11, q = hq & 2047;
  out[(size_t)q * D_MODEL + h * HDIM + d] = f2bf(o / L);
}

// ---------------- host launcher ----------------
extern "C" void kernel_launch(void* const* d_in, const int* in_sizes, int n_in,
                              void* d_out, int out_size, void* d_ws, size_t ws_size,
                              hipStream_t stream) {
  (void)in_sizes; (void)n_in; (void)out_size;
  const float* hidden  = (const float*)d_in[0];
  const float* k_cache = (const float*)d_in[1];
  const float* v_cache = (const float*)d_in[2];
  const float* q_w     = (const float*)d_in[3];
  const float* k_w     = (const float*)d_in[4];
  const float* v_w     = (const float*)d_in[5];
  const float* o_w     = (const float*)d_in[6];
  const float* gate_w  = (const float*)d_in[7];
  const float* up_w    = (const float*)d_in[8];
  const float* down_w  = (const float*)d_in[9];
  const float* ln1     = (const float*)d_in[10];
  const float* ln2     = (const float*)d_in[11];
  const int*   chunkp  = (const int*)d_in[12];

  if (ws_size < 92274688) return;  // 88 MB scratch
  char* ws = (char*)d_ws;
  const size_t MB = 1048576;
  // liveness-packed map (phases: conv/qkv -> rope/attn -> combine/oproj -> mlp)
  unsigned short* qkvpre = (unsigned short*)(ws + 0 * MB);   // 16 MB, live C..F
  unsigned short* keysbf = (unsigned short*)(ws + 16 * MB);  // 16 MB, live D..F
  unsigned short* valst  = (unsigned short*)(ws + 32 * MB);  // 16 MB, live E..F
  unsigned short* pO     = (unsigned short*)(ws + 48 * MB);  // 24 MB, live F..G
  float*          pl     = (float*)(ws + 88 * MB - 393216);  // 384 KB, live F..G
  unsigned short* WQKV   = (unsigned short*)(ws + 72 * MB);  // 16 MB, live B..C
  unsigned short* hn     = (unsigned short*)(ws + 48 * MB);  //  8 MB, live A..C (pre-pO)
  unsigned short* attnbf = (unsigned short*)(ws + 72 * MB);  //  8 MB, live G..I (WQKV dead)
  unsigned short* WO     = (unsigned short*)(ws + 80 * MB);  //  8 MB, live H..I
  unsigned short* h2     = (unsigned short*)(ws + 48 * MB);  //  8 MB, live I..N (pO dead)
  unsigned short* h2n    = (unsigned short*)(ws + 56 * MB);  //  8 MB, live J..L
  unsigned short* WG     = (unsigned short*)(ws + 0 * MB);   // 22 MB, live K..L
  unsigned short* WU     = (unsigned short*)(ws + 22 * MB);  // 22 MB, live K..L
  unsigned short* act    = (unsigned short*)(ws + 64 * MB);  // 22 MB, live L..N
  unsigned short* WD     = (unsigned short*)(ws + 0 * MB);   // 22 MB, live M..N (WG dead)
  float* out = (float*)d_out;

  rmsnorm_k<false><<<S_LEN, 256, 0, stream>>>(hidden, ln1, hn);                    // A
  conv3_k<<<4096, 256, 0, stream>>>(q_w, k_w, v_w, WQKV);                          // B
  gemm_bf<128, 0><<<dim3(16, 32), 256, 0, stream>>>(hn, WQKV, nullptr, qkvpre,     // C
                                                    S_LEN, 4096, D_MODEL);
  rope_k_k<<<(NH * KVLEN * HDIM) / 256, 256, 0, stream>>>(k_cache, qkvpre, keysbf);// D
  vtrans_k<<<dim3(KVLEN / 32, HDIM / 32, NH), 256, 0, stream>>>(v_cache, qkvpre, valst); // E
  attn_k<<<dim3(S_LEN / 64, NH, 3), 256, 0, stream>>>(qkvpre, keysbf, valst,       // F
                                                      chunkp, pO, pl);
  attn_combine<<<(NH * S_LEN * HDIM) / 256, 256, 0, stream>>>(pO, pl, attnbf);     // G
  convw_k<<<2048, 256, 0, stream>>>(o_w, WO);                                      // H
  gemm_bf<64, 1><<<dim3(16, 32), 256, 0, stream>>>(attnbf, WO, hidden, h2,         // I
                                                   S_LEN, D_MODEL, D_MODEL);
  rmsnorm_k<true><<<S_LEN, 256, 0, stream>>>(h2, ln2, h2n);                        // J
  conv2_k<<<11264, 256, 0, stream>>>(gate_w, up_w, WG, WU);                        // K
  gemm_gateup<<<dim3(16, FFDIM / 64), 256, 0, stream>>>(h2n, WG, WU, act);         // L
  convw_k<<<5632, 256, 0, stream>>>(down_w, WD);                                   // M
  gemm_bf<64, 2><<<dim3(16, 32), 256, 0, stream>>>(act, WD, h2, out,               // N
                                                   S_LEN, D_MODEL, FFDIM);
}

// Round 3
// 714.974 us; speedup vs baseline: 1.0320x; 1.0320x over previous
//
#include <hip/hip_runtime.h>

// Decoder layer, MI355X gfx950. GEMMs: bf16 MFMA 16x16x32, m97-style
// global_load_lds(16B) staging. Attention: split-KV x3, key-interleaved LDS
// (packed b64 P writes), constant-max exp2 softmax, fused Q-RoPE.
// R1: attn LDS XOR swizzle (conflicts 11.4M->4.8M).
// R2: dbuf pipeline graft REVERTED (regressed: compiler vmcnt(0) serializes
// prefetch vs ds_read; T3 needs full 8-phase structure, not a graft).
// R3: T1 XCD-aware work placement. attn: 1-D grid, each XCD owns 6 (h,seg)
// pairs x 32 q-blocks (per-XCD KV set ~3MB -> L2-resident). GEMMs: bijective
// swz=(flat%8)*(nwg/8)+flat/8 keeps B-panels per-XCD L2-resident.
// Workspace: 88 MB, liveness-packed (see map in kernel_launch).

#define S_LEN   2048
#define D_MODEL 2048
#define NH      16
#define KVHEADS 8
#define HDIM    128
#define FFDIM   5632
#define PREFIX  2048
#define KVLEN   4096
#define SM_L2E  0.12751744f             // (1/sqrt(128)) * log2(e)
#define MCONST  16.0f                   // fixed softmax max (log2 domain)
#define LN10K_64 0.14391156831212787f   // ln(10000)/64

using bf16x8 = __attribute__((ext_vector_type(8))) short;
using f32x4  = __attribute__((ext_vector_type(4))) float;

__device__ __forceinline__ unsigned f2bf_u(float f) {
  unsigned u = __float_as_uint(f);
  return (u + 0x7fffu + ((u >> 16) & 1u)) >> 16;   // RNE
}
__device__ __forceinline__ unsigned short f2bf(float f) { return (unsigned short)f2bf_u(f); }
__device__ __forceinline__ float bf2f(unsigned short u) {
  return __uint_as_float((unsigned)u << 16);
}
__device__ __forceinline__ unsigned pack2(float a, float b) {
  return f2bf_u(a) | (f2bf_u(b) << 16);
}
__device__ __forceinline__ uint2 pack4(float4 v) {
  uint2 r;
  r.x = pack2(v.x, v.y);
  r.y = pack2(v.z, v.w);
  return r;
}
__device__ __forceinline__ f32x4 mfma16(bf16x8 a, bf16x8 b, f32x4 c) {
  return __builtin_amdgcn_mfma_f32_16x16x32_bf16(a, b, c, 0, 0, 0);
}
__device__ __forceinline__ void gl2lds16(const unsigned short* g, unsigned short* l) {
  __builtin_amdgcn_global_load_lds(
      (__attribute__((address_space(1))) void*)(unsigned short*)g,
      (__attribute__((address_space(3))) void*)l, 16, 0, 0);
}

// ---------------- fp32 -> bf16 weight conversion ----------------
__device__ __forceinline__ void conv_body(const float* __restrict__ src,
                                          unsigned short* __restrict__ dst,
                                          int bseg, int tid) {
  size_t i = (size_t)bseg * 256 + tid;
  const float4* s4 = (const float4*)src;
  float4 a = s4[2 * i], b = s4[2 * i + 1];
  uint2 lo = pack4(a), hi = pack4(b);
  ((uint4*)dst)[i] = make_uint4(lo.x, lo.y, hi.x, hi.y);
}
__global__ __launch_bounds__(256) void convw_k(const float* __restrict__ src,
                                               unsigned short* __restrict__ dst) {
  conv_body(src, dst, blockIdx.x, threadIdx.x);
}
// q (2048 blocks) + k (1024) + v (1024) -> fused WQKV
__global__ __launch_bounds__(256) void conv3_k(const float* __restrict__ q,
                                               const float* __restrict__ k,
                                               const float* __restrict__ v,
                                               unsigned short* __restrict__ dst) {
  int b = blockIdx.x;
  if (b < 2048)      conv_body(q, dst, b, threadIdx.x);
  else if (b < 3072) conv_body(k, dst + (size_t)2048 * 2048, b - 2048, threadIdx.x);
  else               conv_body(v, dst + (size_t)3072 * 2048, b - 3072, threadIdx.x);
}
// gate (5632) + up (5632)
__global__ __launch_bounds__(256) void conv2_k(const float* __restrict__ g,
                                               const float* __restrict__ u,
                                               unsigned short* __restrict__ wg,
                                               unsigned short* __restrict__ wu) {
  int b = blockIdx.x;
  if (b < 5632) conv_body(g, wg, b, threadIdx.x);
  else          conv_body(u, wu, b - 5632, threadIdx.x);
}

// ---------------- RMSNorm -> bf16 out; input fp32 or bf16 ----------------
template <bool INBF>
__global__ __launch_bounds__(256) void rmsnorm_k(const void* __restrict__ xin,
                                                 const float* __restrict__ w,
                                                 unsigned short* __restrict__ out) {
  const int row = blockIdx.x, tid = threadIdx.x;
  float v[8];
  if constexpr (INBF) {
    const unsigned short* xr = (const unsigned short*)xin + (size_t)row * D_MODEL;
    uint4 u = ((const uint4*)xr)[tid];
    v[0] = bf2f((unsigned short)(u.x & 0xffff)); v[1] = bf2f((unsigned short)(u.x >> 16));
    v[2] = bf2f((unsigned short)(u.y & 0xffff)); v[3] = bf2f((unsigned short)(u.y >> 16));
    v[4] = bf2f((unsigned short)(u.z & 0xffff)); v[5] = bf2f((unsigned short)(u.z >> 16));
    v[6] = bf2f((unsigned short)(u.w & 0xffff)); v[7] = bf2f((unsigned short)(u.w >> 16));
  } else {
    const float4* xr = (const float4*)((const float*)xin + (size_t)row * D_MODEL);
    float4 a = xr[2 * tid], b = xr[2 * tid + 1];
    v[0] = a.x; v[1] = a.y; v[2] = a.z; v[3] = a.w;
    v[4] = b.x; v[5] = b.y; v[6] = b.z; v[7] = b.w;
  }
  float ss = 0.f;
#pragma unroll
  for (int i = 0; i < 8; i++) ss += v[i] * v[i];
#pragma unroll
  for (int off = 1; off < 64; off <<= 1) ss += __shfl_xor(ss, off);
  __shared__ float red[4];
  if ((tid & 63) == 0) red[tid >> 6] = ss;
  __syncthreads();
  const float sc = rsqrtf((red[0] + red[1] + red[2] + red[3]) * (1.0f / D_MODEL) + 1e-5f);
  const float4* w4 = (const float4*)w;
  float4 wa = w4[2 * tid], wb = w4[2 * tid + 1];
  float4 oa = make_float4(v[0]*sc*wa.x, v[1]*sc*wa.y, v[2]*sc*wa.z, v[3]*sc*wa.w);
  float4 ob = make_float4(v[4]*sc*wb.x, v[5]*sc*wb.y, v[6]*sc*wb.z, v[7]*sc*wb.w);
  uint2 lo = pack4(oa), hi = pack4(ob);
  ((uint4*)(out + (size_t)row * D_MODEL))[tid] = make_uint4(lo.x, lo.y, hi.x, hi.y);
}

// ---------------- GEMM: C[M,N] = A[M,K](bf16) @ B[N,K](bf16)^T ----------------
// R3: XCD-aware block remap (requires nwg % 8 == 0, true for all launches).
template <int BN, int EPI>
__global__ __launch_bounds__(256) void gemm_bf(const unsigned short* __restrict__ A,
                                               const unsigned short* __restrict__ B,
                                               const void* __restrict__ res,
                                               void* __restrict__ C,
                                               int M, int N, int K) {
  constexpr int NI = BN / 32;
  __shared__ __align__(16) unsigned short lA[128 * 32];
  __shared__ __align__(16) unsigned short lB[BN * 32];
  const int tid = threadIdx.x, lane = tid & 63, wave = tid >> 6;
  const int r16 = lane & 15, q4 = lane >> 4;
  const int wm = wave >> 1, wn = wave & 1;
  // T1 swizzle: XCD (flat%8) gets contiguous chunk of the by-major grid
  const int nwg = gridDim.x * gridDim.y;
  const int flat = blockIdx.y * gridDim.x + blockIdx.x;
  const int swz = (flat & 7) * (nwg >> 3) + (flat >> 3);
  const int m0 = (swz % gridDim.x) * 128, n0 = (swz / gridDim.x) * BN;

  const int lr = lane >> 2;
  const int lc = (lane & 3) * 8;
  const unsigned short* gA0 = A + (size_t)(m0 + wave * 16 + lr) * K + lc;
  const unsigned short* gA1 = A + (size_t)(m0 + 64 + wave * 16 + lr) * K + lc;
  unsigned short* lA0 = lA + (wave * 16) * 32;
  unsigned short* lA1 = lA + (64 + wave * 16) * 32;
  const unsigned short* gB0 = B + (size_t)(n0 + wave * 16 + lr) * K + lc;
  const unsigned short* gB1 = B + (size_t)(n0 + 64 + wave * 16 + lr) * K + lc;
  unsigned short* lB0 = lB + (wave * 16) * 32;
  unsigned short* lB1 = lB + (64 + wave * 16) * 32;

  f32x4 acc[4][NI];
#pragma unroll
  for (int i = 0; i < 4; i++)
#pragma unroll
    for (int j = 0; j < NI; j++) acc[i][j] = f32x4{0.f, 0.f, 0.f, 0.f};

  for (int k0 = 0; k0 < K; k0 += 32) {
    gl2lds16(gA0, lA0);
    gl2lds16(gA1, lA1);
    gl2lds16(gB0, lB0);
    if constexpr (BN == 128) gl2lds16(gB1, lB1);
    gA0 += 32; gA1 += 32; gB0 += 32;
    if constexpr (BN == 128) gB1 += 32;
    __syncthreads();
    bf16x8 af[4], bfr[NI];
#pragma unroll
    for (int mi = 0; mi < 4; mi++)
      af[mi] = *(const bf16x8*)&lA[(wm * 64 + mi * 16 + r16) * 32 + q4 * 8];
#pragma unroll
    for (int ni = 0; ni < NI; ni++)
      bfr[ni] = *(const bf16x8*)&lB[(wn * (BN / 2) + ni * 16 + r16) * 32 + q4 * 8];
#pragma unroll
    for (int mi = 0; mi < 4; mi++)
#pragma unroll
      for (int ni = 0; ni < NI; ni++)
        acc[mi][ni] = mfma16(af[mi], bfr[ni], acc[mi][ni]);
    __syncthreads();
  }
#pragma unroll
  for (int mi = 0; mi < 4; mi++)
#pragma unroll
    for (int ni = 0; ni < NI; ni++) {
      int col = n0 + wn * (BN / 2) + ni * 16 + r16;
#pragma unroll
      for (int rr = 0; rr < 4; rr++) {
        int row = m0 + wm * 64 + mi * 16 + q4 * 4 + rr;
        size_t idx = (size_t)row * N + col;
        float v = acc[mi][ni][rr];
        if constexpr (EPI == 0) {
          ((unsigned short*)C)[idx] = f2bf(v);
        } else if constexpr (EPI == 1) {
          ((unsigned short*)C)[idx] = f2bf(v + ((const float*)res)[idx]);
        } else {
          ((float*)C)[idx] = v + bf2f(((const unsigned short*)res)[idx]);
        }
      }
    }
}

// ---------------- Fused gate/up GEMM + silu*mul -> bf16 (BM=128, BN=64) ----------------
// R3: XCD-aware block remap (nwg = 16*88 = 1408, %8 == 0).
__global__ __launch_bounds__(256) void gemm_gateup(const unsigned short* __restrict__ A,
                                                   const unsigned short* __restrict__ Bg,
                                                   const unsigned short* __restrict__ Bu,
                                                   unsigned short* __restrict__ act) {
  __shared__ __align__(16) unsigned short lA[128 * 32];
  __shared__ __align__(16) unsigned short lG[64 * 32];
  __shared__ __align__(16) unsigned short lU[64 * 32];
  const int tid = threadIdx.x, lane = tid & 63, wave = tid >> 6;
  const int r16 = lane & 15, q4 = lane >> 4;
  const int wm = wave >> 1, wn = wave & 1;
  const int nwg = gridDim.x * gridDim.y;
  const int flat = blockIdx.y * gridDim.x + blockIdx.x;
  const int swz = (flat & 7) * (nwg >> 3) + (flat >> 3);
  const int m0 = (swz % gridDim.x) * 128, n0 = (swz / gridDim.x) * 64;
  const int K = D_MODEL;

  const int lr = lane >> 2, lc = (lane & 3) * 8;
  const unsigned short* gA0 = A + (size_t)(m0 + wave * 16 + lr) * K + lc;
  const unsigned short* gA1 = A + (size_t)(m0 + 64 + wave * 16 + lr) * K + lc;
  unsigned short* lA0 = lA + (wave * 16) * 32;
  unsigned short* lA1 = lA + (64 + wave * 16) * 32;
  const unsigned short* gG0 = Bg + (size_t)(n0 + wave * 16 + lr) * K + lc;
  const unsigned short* gU0 = Bu + (size_t)(n0 + wave * 16 + lr) * K + lc;
  unsigned short* lG0 = lG + (wave * 16) * 32;
  unsigned short* lU0 = lU + (wave * 16) * 32;

  f32x4 ag[4][2], au[4][2];
#pragma unroll
  for (int i = 0; i < 4; i++)
#pragma unroll
    for (int j = 0; j < 2; j++) { ag[i][j] = f32x4{0.f,0.f,0.f,0.f}; au[i][j] = f32x4{0.f,0.f,0.f,0.f}; }

  for (int k0 = 0; k0 < K; k0 += 32) {
    gl2lds16(gA0, lA0);
    gl2lds16(gA1, lA1);
    gl2lds16(gG0, lG0);
    gl2lds16(gU0, lU0);
    gA0 += 32; gA1 += 32; gG0 += 32; gU0 += 32;
    __syncthreads();
    bf16x8 af[4], bg2[2], bu2[2];
#pragma unroll
    for (int mi = 0; mi < 4; mi++)
      af[mi] = *(const bf16x8*)&lA[(wm * 64 + mi * 16 + r16) * 32 + q4 * 8];
#pragma unroll
    for (int ni = 0; ni < 2; ni++) {
      int r = (wn * 32 + ni * 16 + r16) * 32 + q4 * 8;
      bg2[ni] = *(const bf16x8*)&lG[r];
      bu2[ni] = *(const bf16x8*)&lU[r];
    }
#pragma unroll
    for (int mi = 0; mi < 4; mi++)
#pragma unroll
      for (int ni = 0; ni < 2; ni++) {
        ag[mi][ni] = mfma16(af[mi], bg2[ni], ag[mi][ni]);
        au[mi][ni] = mfma16(af[mi], bu2[ni], au[mi][ni]);
      }
    __syncthreads();
  }
#pragma unroll
  for (int mi = 0; mi < 4; mi++)
#pragma unroll
    for (int ni = 0; ni < 2; ni++) {
      int col = n0 + wn * 32 + ni * 16 + r16;
#pragma unroll
      for (int rr = 0; rr < 4; rr++) {
        int row = m0 + wm * 64 + mi * 16 + q4 * 4 + rr;
        float g = ag[mi][ni][rr], u = au[mi][ni][rr];
        float sil = g / (1.0f + __expf(-g));
        act[(size_t)row * FFDIM + col] = f2bf(sil * u);
      }
    }
}

// -------- RoPE for keys: fp32 cache + bf16 new (GQA repeat) -> keys_bf[H][KV][HD] --------
__global__ __launch_bounds__(256) void rope_k_k(const float* __restrict__ k_cache,
                                                const unsigned short* __restrict__ qkv,
                                                unsigned short* __restrict__ keys_bf) {
  int idx = blockIdx.x * 256 + threadIdx.x;        // [h][j][d]
  int d = idx & 127, j = (idx >> 7) & 4095, h = idx >> 19;
  int dd = d & 63;
  float inv = __expf(-(float)dd * LN10K_64);
  float ang = (float)j * inv;
  float c = cosf(ang), sn = sinf(ang);
  float x, xr;
  if (j < PREFIX) {
    const float* row = k_cache + ((size_t)h * PREFIX + j) * HDIM;
    x = row[d];
    xr = (d < 64) ? -row[d + 64] : row[d - 64];
  } else {
    const unsigned short* row = qkv + (size_t)(j - PREFIX) * 4096 + 2048 + (h >> 1) * HDIM;
    x = bf2f(row[d]);
    xr = (d < 64) ? -bf2f(row[d + 64]) : bf2f(row[d - 64]);
  }
  keys_bf[idx] = f2bf(x * c + xr * sn);
}

// -------- V transpose: fp32 cache + bf16 new -> vals_t[H][HD][KV] bf16 --------
__global__ __launch_bounds__(256) void vtrans_k(const float* __restrict__ v_cache,
                                                const unsigned short* __restrict__ qkv,
                                                unsigned short* __restrict__ vals_t) {
  __shared__ float tile[32][33];
  const int h = blockIdx.z, j0 = blockIdx.x * 32, d0 = blockIdx.y * 32;
  const int t = threadIdx.x;
#pragma unroll
  for (int i = 0; i < 4; i++) {
    int e = i * 256 + t;
    int jj = e >> 5, dd = e & 31;
    float v;
    if (j0 < PREFIX)
      v = v_cache[((size_t)h * PREFIX + j0 + jj) * HDIM + d0 + dd];
    else
      v = bf2f(qkv[(size_t)(j0 - PREFIX + jj) * 4096 + 3072 + (h >> 1) * HDIM + d0 + dd]);
    tile[jj][dd] = v;
  }
  __syncthreads();
#pragma unroll
  for (int i = 0; i < 4; i++) {
    int e = i * 256 + t;
    int dd = e >> 5, jj = e & 31;
    vals_t[((size_t)h * HDIM + d0 + dd) * KVLEN + j0 + jj] = f2bf(tile[jj][dd]);
  }
}

// ---------------- Split-KV flash attention v2 ----------------
// 1-D grid 1536 = 8 XCDs x 6 (h,seg) pairs x 32 q-blocks. XCD x owns pairs
// [6x, 6x+6): its 32 q-blocks per pair share one K/V slab (~0.5 MB) -> per-XCD
// working set ~3 MB, L2-resident. Key-interleaved K staging (LDS row rho
// holds key (rho&15)*4 + (rho>>4)); constant-max exp2 softmax; fused Q-RoPE.
// LDS layouts (XOR-swizzled, slot ^= row&7, 16B slots):
//   lK [64 rho][128 dims]  256B rows — pre-swizzled global source
//   lV [128 dim][64 keys]  128B rows — pre-swizzled global source
//   lP [wave][16 q][64 keys] 128B rows — swizzled ds_write_b64 / ds_read_b128
__global__ __launch_bounds__(256) void attn_k(const unsigned short* __restrict__ qkv,
                                              const unsigned short* __restrict__ keys,
                                              const unsigned short* __restrict__ valst,
                                              const int* __restrict__ chunkp,
                                              unsigned short* __restrict__ pO,
                                              float* __restrict__ pl) {
  __shared__ __align__(16) unsigned short lK[64 * 128];    // [rho][dims], swizzled
  __shared__ __align__(16) unsigned short lV[128 * 64];    // [dim][keys], swizzled
  __shared__ __align__(16) unsigned short lP[4][16 * 64];  // [wave][q][keys], swizzled
  // ---- XCD-aware work mapping (grid = 1536 1-D) ----
  const int flat = blockIdx.x;
  const int xcd = flat & 7, ii = flat >> 3;        // ii in [0,192)
  const int pair = xcd * 6 + (ii >> 5);            // 48 (h,seg) pairs
  const int h = pair & 15, seg = pair >> 4;
  const int q0 = (ii & 31) * 64;
  const int tid = threadIdx.x, wave = tid >> 6, lane = tid & 63;
  const int r16 = lane & 15, q4 = lane >> 4;
  const int chunk = chunkp[0];
  const int sw = (r16 & 7) << 4;                 // read-side XOR swizzle

  // ---- Q load + RoPE (A-frag row = q0+wave*16+r16, dims ks*32+q4*8..+7) ----
  const int qrow = q0 + wave * 16 + r16;
  const unsigned short* qr = qkv + (size_t)qrow * 4096 + h * HDIM;
  float qx[4][8];
#pragma unroll
  for (int ks = 0; ks < 4; ks++) {
    bf16x8 raw = *(const bf16x8*)(qr + ks * 32 + q4 * 8);
#pragma unroll
    for (int j = 0; j < 8; j++) qx[ks][j] = bf2f((unsigned short)raw[j]);
  }
  const float pos = (float)(PREFIX + qrow);
  bf16x8 qf[4];
#pragma unroll
  for (int ks = 0; ks < 4; ks++)
#pragma unroll
    for (int j = 0; j < 8; j++) {
      int d = ks * 32 + q4 * 8 + j;
      float inv = __expf(-(float)(d & 63) * LN10K_64);
      float ang = pos * inv;
      float c = cosf(ang), sn = sinf(ang);
      float other = qx[ks ^ 2][j];
      float rot = (ks < 2) ? -other : other;
      qf[ks][j] = (short)f2bf(qx[ks][j] * c + rot * sn);
    }

  float lrow[4] = {0.f, 0.f, 0.f, 0.f};
  f32x4 oacc[8];
#pragma unroll
  for (int ni = 0; ni < 8; ni++) oacc[ni] = f32x4{0.f, 0.f, 0.f, 0.f};

  const int irow_base = q0 + wave * 16 + q4 * 4;   // C-layout rows
  const unsigned short* Kh = keys + (size_t)h * KVLEN * HDIM;
  const unsigned short* Vh = valst + (size_t)h * HDIM * KVLEN;

  // ---- staging bases (linear LDS dest; XOR-swizzled global source) ----
  const int krow = wave * 4 + (lane >> 4);                       // rho & 15
  const unsigned short* kSrc = Kh + (size_t)(krow * 4) * HDIM
                               + (((lane & 15) ^ (krow & 7)) * 8);
  unsigned short* kDst = lK + (wave * 4) * 128;
  const int vrow = wave * 8 + (lane >> 3);
  const unsigned short* vSrc = Vh + (size_t)vrow * KVLEN
                               + (((lane & 7) ^ ((lane >> 3) & 7)) * 8);
  unsigned short* vDst = lV + (wave * 8) * 64;

  int kt0, ktN;
  if (seg == 0)      { kt0 = 0;    ktN = 1024; }
  else if (seg == 1) { kt0 = 1024; ktN = 2048; }
  else { int cs = (q0 / chunk) * chunk; kt0 = PREFIX + cs; ktN = PREFIX + q0 + 64; }

  for (int kt = kt0; kt < ktN; kt += 64) {
    const bool domask = (seg == 2) && (kt - PREFIX + 64 > q0);
    // K stage: 4 rows (256B each) per wave per iteration
#pragma unroll
    for (int i = 0; i < 4; i++)
      gl2lds16(kSrc + (size_t)(kt + i) * HDIM, kDst + i * 16 * 128);
    // V stage: 8 rows (128B each) per wave per iteration
#pragma unroll
    for (int i = 0; i < 4; i++)
      gl2lds16(vSrc + (size_t)i * 32 * KVLEN + kt, vDst + i * 32 * 64);
    __syncthreads();
    // QK — kf row j*16+r16 (256B rows), dim bytes (ks*64+q4*16)^sw
    f32x4 s[4];
#pragma unroll
    for (int j = 0; j < 4; j++) s[j] = f32x4{0.f, 0.f, 0.f, 0.f};
#pragma unroll
    for (int ks = 0; ks < 4; ks++)
#pragma unroll
      for (int j = 0; j < 4; j++) {
        bf16x8 kf = *(const bf16x8*)((const char*)lK + (j * 16 + r16) * 256
                                     + ((ks * 64 + q4 * 16) ^ sw));
        s[j] = mfma16(qf[ks], kf, s[j]);
      }
    // constant-max softmax; lane's cols = keys kt + r16*4 + j
    const int klb = kt - PREFIX + r16 * 4;
#pragma unroll
    for (int rr = 0; rr < 4; rr++) {
      float e0 = fmaf(s[0][rr], SM_L2E, -MCONST);
      float e1 = fmaf(s[1][rr], SM_L2E, -MCONST);
      float e2 = fmaf(s[2][rr], SM_L2E, -MCONST);
      float e3 = fmaf(s[3][rr], SM_L2E, -MCONST);
      if (domask) {
        int irow = irow_base + rr;
        if (klb     > irow) e0 = -1e30f;
        if (klb + 1 > irow) e1 = -1e30f;
        if (klb + 2 > irow) e2 = -1e30f;
        if (klb + 3 > irow) e3 = -1e30f;
      }
      float p0 = exp2f(e0), p1 = exp2f(e1), p2 = exp2f(e2), p3 = exp2f(e3);
      lrow[rr] += (p0 + p1) + (p2 + p3);
      uint2 pk = make_uint2(pack2(p0, p1), pack2(p2, p3));
      int qrw = q4 * 4 + rr;                         // q-row within 16-tile
      *(uint2*)((char*)lP[wave] + qrw * 128 + ((r16 * 8) ^ ((qrw & 7) << 4))) = pk;
    }
    // PV (P exchange is intra-wave; DS ops are in-order per wave)
    bf16x8 pf0 = *(const bf16x8*)((const char*)lP[wave] + r16 * 128
                                  + ((q4 * 16) ^ sw));
    bf16x8 pf1 = *(const bf16x8*)((const char*)lP[wave] + r16 * 128
                                  + ((64 + q4 * 16) ^ sw));
#pragma unroll
    for (int ni = 0; ni < 8; ni++) {
      bf16x8 v0 = *(const bf16x8*)((const char*)lV + (ni * 16 + r16) * 128
                                   + ((q4 * 16) ^ sw));
      oacc[ni] = mfma16(pf0, v0, oacc[ni]);
      bf16x8 v1 = *(const bf16x8*)((const char*)lV + (ni * 16 + r16) * 128
                                   + ((64 + q4 * 16) ^ sw));
      oacc[ni] = mfma16(pf1, v1, oacc[ni]);
    }
    __syncthreads();   // protect lK/lV before next tile's staging
  }

  // deferred cross-lane l reduction (over the 16 r16 lanes)
#pragma unroll
  for (int rr = 0; rr < 4; rr++) {
    lrow[rr] += __shfl_xor(lrow[rr], 1);
    lrow[rr] += __shfl_xor(lrow[rr], 2);
    lrow[rr] += __shfl_xor(lrow[rr], 4);
    lrow[rr] += __shfl_xor(lrow[rr], 8);
  }
  const size_t base = (size_t)(seg * NH + h) * S_LEN;
#pragma unroll
  for (int ni = 0; ni < 8; ni++)
#pragma unroll
    for (int rr = 0; rr < 4; rr++)
      pO[(base + irow_base + rr) * HDIM + ni * 16 + r16] = f2bf(oacc[ni][rr]);
  if (r16 == 0) {
#pragma unroll
    for (int rr = 0; rr < 4; rr++) pl[base + irow_base + rr] = lrow[rr];
  }
}

// ---------------- combine 3 split-KV partials (same const max) ----------------
__global__ __launch_bounds__(256) void attn_combine(const unsigned short* __restrict__ pO,
                                                    const float* __restrict__ pl,
                                                    unsigned short* __restrict__ out) {
  int idx = blockIdx.x * 256 + threadIdx.x;        // [h][q][d]
  int d = idx & 127, hq = idx >> 7;                // hq = h*2048+q
  const int R = NH * S_LEN;
  float L = pl[hq] + pl[hq + R] + pl[hq + 2 * R];
  float o = bf2f(pO[(size_t)hq * HDIM + d])
          + bf2f(pO[(size_t)(hq + R) * HDIM + d])
          + bf2f(pO[(size_t)(hq + 2 * R) * HDIM + d]);
  int h = hq >> 11, q = hq & 2047;
  out[(size_t)q * D_MODEL + h * HDIM + d] = f2bf(o / L);
}

// ---------------- host launcher ----------------
extern "C" void kernel_launch(void* const* d_in, const int* in_sizes, int n_in,
                              void* d_out, int out_size, void* d_ws, size_t ws_size,
                              hipStream_t stream) {
  (void)in_sizes; (void)n_in; (void)out_size;
  const float* hidden  = (const float*)d_in[0];
  const float* k_cache = (const float*)d_in[1];
  const float* v_cache = (const float*)d_in[2];
  const float* q_w     = (const float*)d_in[3];
  const float* k_w     = (const float*)d_in[4];
  const float* v_w     = (const float*)d_in[5];
  const float* o_w     = (const float*)d_in[6];
  const float* gate_w  = (const float*)d_in[7];
  const float* up_w    = (const float*)d_in[8];
  const float* down_w  = (const float*)d_in[9];
  const float* ln1     = (const float*)d_in[10];
  const float* ln2     = (const float*)d_in[11];
  const int*   chunkp  = (const int*)d_in[12];

  if (ws_size < 92274688) return;  // 88 MB scratch
  char* ws = (char*)d_ws;
  const size_t MB = 1048576;
  // liveness-packed map (phases: conv/qkv -> rope/attn -> combine/oproj -> mlp)
  unsigned short* qkvpre = (unsigned short*)(ws + 0 * MB);   // 16 MB, live C..F
  unsigned short* keysbf = (unsigned short*)(ws + 16 * MB);  // 16 MB, live D..F
  unsigned short* valst  = (unsigned short*)(ws + 32 * MB);  // 16 MB, live E..F
  unsigned short* pO     = (unsigned short*)(ws + 48 * MB);  // 24 MB, live F..G
  float*          pl     = (float*)(ws + 88 * MB - 393216);  // 384 KB, live F..G
  unsigned short* WQKV   = (unsigned short*)(ws + 72 * MB);  // 16 MB, live B..C
  unsigned short* hn     = (unsigned short*)(ws + 48 * MB);  //  8 MB, live A..C (pre-pO)
  unsigned short* attnbf = (unsigned short*)(ws + 72 * MB);  //  8 MB, live G..I (WQKV dead)
  unsigned short* WO     = (unsigned short*)(ws + 80 * MB);  //  8 MB, live H..I
  unsigned short* h2     = (unsigned short*)(ws + 48 * MB);  //  8 MB, live I..N (pO dead)
  unsigned short* h2n    = (unsigned short*)(ws + 56 * MB);  //  8 MB, live J..L
  unsigned short* WG     = (unsigned short*)(ws + 0 * MB);   // 22 MB, live K..L
  unsigned short* WU     = (unsigned short*)(ws + 22 * MB);  // 22 MB, live K..L
  unsigned short* act    = (unsigned short*)(ws + 64 * MB);  // 22 MB, live L..N
  unsigned short* WD     = (unsigned short*)(ws + 0 * MB);   // 22 MB, live M..N (WG dead)
  float* out = (float*)d_out;

  rmsnorm_k<false><<<S_LEN, 256, 0, stream>>>(hidden, ln1, hn);                    // A
  conv3_k<<<4096, 256, 0, stream>>>(q_w, k_w, v_w, WQKV);                          // B
  gemm_bf<128, 0><<<dim3(16, 32), 256, 0, stream>>>(hn, WQKV, nullptr, qkvpre,     // C
                                                    S_LEN, 4096, D_MODEL);
  rope_k_k<<<(NH * KVLEN * HDIM) / 256, 256, 0, stream>>>(k_cache, qkvpre, keysbf);// D
  vtrans_k<<<dim3(KVLEN / 32, HDIM / 32, NH), 256, 0, stream>>>(v_cache, qkvpre, valst); // E
  attn_k<<<1536, 256, 0, stream>>>(qkvpre, keysbf, valst, chunkp, pO, pl);         // F
  attn_combine<<<(NH * S_LEN * HDIM) / 256, 256, 0, stream>>>(pO, pl, attnbf);     // G
  convw_k<<<2048, 256, 0, stream>>>(o_w, WO);                                      // H
  gemm_bf<64, 1><<<dim3(16, 32), 256, 0, stream>>>(attnbf, WO, hidden, h2,         // I
                                                   S_LEN, D_MODEL, D_MODEL);
  rmsnorm_k<true><<<S_LEN, 256, 0, stream>>>(h2, ln2, h2n);                        // J
  conv2_k<<<11264, 256, 0, stream>>>(gate_w, up_w, WG, WU);                        // K
  gemm_gateup<<<dim3(16, FFDIM / 64), 256, 0, stream>>>(h2n, WG, WU, act);         // L
  convw_k<<<5632, 256, 0, stream>>>(down_w, WD);                                   // M
  gemm_bf<64, 2><<<dim3(16, 32), 256, 0, stream>>>(act, WD, h2, out,               // N
                                                   S_LEN, D_MODEL, FFDIM);
}

// Round 4
// 697.447 us; speedup vs baseline: 1.0579x; 1.0251x over previous
//
#include <hip/hip_runtime.h>

// Decoder layer, MI355X gfx950. GEMMs: bf16 MFMA 16x16x32, m97-style
// global_load_lds(16B) staging. Attention: split-KV x3, key-interleaved LDS
// (packed b64 P writes), constant-max exp2 softmax, fused Q-RoPE.
// R1: attn LDS XOR swizzle (conflicts 11.4M->4.8M).
// R2: dbuf pipeline graft REVERTED (compiler vmcnt(0) serializes it).
// R3: T1 XCD-aware placement. attn FETCH 117->30MB (L2-resident KV confirmed)
// but pair->XCD layout was imbalanced (XCD0-4: 3072 tiles, XCD6-7: 864).
// R4: balanced XCD assignment: each XCD owns heads {2x,2x+1} for ALL segs
// = 2x(512+512+144) = 2336 tiles each (exactly total/8). Footprint 4MB/XCD.
// Workspace: 88 MB, liveness-packed (see map in kernel_launch).

#define S_LEN   2048
#define D_MODEL 2048
#define NH      16
#define KVHEADS 8
#define HDIM    128
#define FFDIM   5632
#define PREFIX  2048
#define KVLEN   4096
#define SM_L2E  0.12751744f             // (1/sqrt(128)) * log2(e)
#define MCONST  16.0f                   // fixed softmax max (log2 domain)
#define LN10K_64 0.14391156831212787f   // ln(10000)/64

using bf16x8 = __attribute__((ext_vector_type(8))) short;
using f32x4  = __attribute__((ext_vector_type(4))) float;

__device__ __forceinline__ unsigned f2bf_u(float f) {
  unsigned u = __float_as_uint(f);
  return (u + 0x7fffu + ((u >> 16) & 1u)) >> 16;   // RNE
}
__device__ __forceinline__ unsigned short f2bf(float f) { return (unsigned short)f2bf_u(f); }
__device__ __forceinline__ float bf2f(unsigned short u) {
  return __uint_as_float((unsigned)u << 16);
}
__device__ __forceinline__ unsigned pack2(float a, float b) {
  return f2bf_u(a) | (f2bf_u(b) << 16);
}
__device__ __forceinline__ uint2 pack4(float4 v) {
  uint2 r;
  r.x = pack2(v.x, v.y);
  r.y = pack2(v.z, v.w);
  return r;
}
__device__ __forceinline__ f32x4 mfma16(bf16x8 a, bf16x8 b, f32x4 c) {
  return __builtin_amdgcn_mfma_f32_16x16x32_bf16(a, b, c, 0, 0, 0);
}
__device__ __forceinline__ void gl2lds16(const unsigned short* g, unsigned short* l) {
  __builtin_amdgcn_global_load_lds(
      (__attribute__((address_space(1))) void*)(unsigned short*)g,
      (__attribute__((address_space(3))) void*)l, 16, 0, 0);
}

// ---------------- fp32 -> bf16 weight conversion ----------------
__device__ __forceinline__ void conv_body(const float* __restrict__ src,
                                          unsigned short* __restrict__ dst,
                                          int bseg, int tid) {
  size_t i = (size_t)bseg * 256 + tid;
  const float4* s4 = (const float4*)src;
  float4 a = s4[2 * i], b = s4[2 * i + 1];
  uint2 lo = pack4(a), hi = pack4(b);
  ((uint4*)dst)[i] = make_uint4(lo.x, lo.y, hi.x, hi.y);
}
__global__ __launch_bounds__(256) void convw_k(const float* __restrict__ src,
                                               unsigned short* __restrict__ dst) {
  conv_body(src, dst, blockIdx.x, threadIdx.x);
}
// q (2048 blocks) + k (1024) + v (1024) -> fused WQKV
__global__ __launch_bounds__(256) void conv3_k(const float* __restrict__ q,
                                               const float* __restrict__ k,
                                               const float* __restrict__ v,
                                               unsigned short* __restrict__ dst) {
  int b = blockIdx.x;
  if (b < 2048)      conv_body(q, dst, b, threadIdx.x);
  else if (b < 3072) conv_body(k, dst + (size_t)2048 * 2048, b - 2048, threadIdx.x);
  else               conv_body(v, dst + (size_t)3072 * 2048, b - 3072, threadIdx.x);
}
// gate (5632) + up (5632)
__global__ __launch_bounds__(256) void conv2_k(const float* __restrict__ g,
                                               const float* __restrict__ u,
                                               unsigned short* __restrict__ wg,
                                               unsigned short* __restrict__ wu) {
  int b = blockIdx.x;
  if (b < 5632) conv_body(g, wg, b, threadIdx.x);
  else          conv_body(u, wu, b - 5632, threadIdx.x);
}

// ---------------- RMSNorm -> bf16 out; input fp32 or bf16 ----------------
template <bool INBF>
__global__ __launch_bounds__(256) void rmsnorm_k(const void* __restrict__ xin,
                                                 const float* __restrict__ w,
                                                 unsigned short* __restrict__ out) {
  const int row = blockIdx.x, tid = threadIdx.x;
  float v[8];
  if constexpr (INBF) {
    const unsigned short* xr = (const unsigned short*)xin + (size_t)row * D_MODEL;
    uint4 u = ((const uint4*)xr)[tid];
    v[0] = bf2f((unsigned short)(u.x & 0xffff)); v[1] = bf2f((unsigned short)(u.x >> 16));
    v[2] = bf2f((unsigned short)(u.y & 0xffff)); v[3] = bf2f((unsigned short)(u.y >> 16));
    v[4] = bf2f((unsigned short)(u.z & 0xffff)); v[5] = bf2f((unsigned short)(u.z >> 16));
    v[6] = bf2f((unsigned short)(u.w & 0xffff)); v[7] = bf2f((unsigned short)(u.w >> 16));
  } else {
    const float4* xr = (const float4*)((const float*)xin + (size_t)row * D_MODEL);
    float4 a = xr[2 * tid], b = xr[2 * tid + 1];
    v[0] = a.x; v[1] = a.y; v[2] = a.z; v[3] = a.w;
    v[4] = b.x; v[5] = b.y; v[6] = b.z; v[7] = b.w;
  }
  float ss = 0.f;
#pragma unroll
  for (int i = 0; i < 8; i++) ss += v[i] * v[i];
#pragma unroll
  for (int off = 1; off < 64; off <<= 1) ss += __shfl_xor(ss, off);
  __shared__ float red[4];
  if ((tid & 63) == 0) red[tid >> 6] = ss;
  __syncthreads();
  const float sc = rsqrtf((red[0] + red[1] + red[2] + red[3]) * (1.0f / D_MODEL) + 1e-5f);
  const float4* w4 = (const float4*)w;
  float4 wa = w4[2 * tid], wb = w4[2 * tid + 1];
  float4 oa = make_float4(v[0]*sc*wa.x, v[1]*sc*wa.y, v[2]*sc*wa.z, v[3]*sc*wa.w);
  float4 ob = make_float4(v[4]*sc*wb.x, v[5]*sc*wb.y, v[6]*sc*wb.z, v[7]*sc*wb.w);
  uint2 lo = pack4(oa), hi = pack4(ob);
  ((uint4*)(out + (size_t)row * D_MODEL))[tid] = make_uint4(lo.x, lo.y, hi.x, hi.y);
}

// ---------------- GEMM: C[M,N] = A[M,K](bf16) @ B[N,K](bf16)^T ----------------
// R3: XCD-aware block remap (requires nwg % 8 == 0, true for all launches).
template <int BN, int EPI>
__global__ __launch_bounds__(256) void gemm_bf(const unsigned short* __restrict__ A,
                                               const unsigned short* __restrict__ B,
                                               const void* __restrict__ res,
                                               void* __restrict__ C,
                                               int M, int N, int K) {
  constexpr int NI = BN / 32;
  __shared__ __align__(16) unsigned short lA[128 * 32];
  __shared__ __align__(16) unsigned short lB[BN * 32];
  const int tid = threadIdx.x, lane = tid & 63, wave = tid >> 6;
  const int r16 = lane & 15, q4 = lane >> 4;
  const int wm = wave >> 1, wn = wave & 1;
  // T1 swizzle: XCD (flat%8) gets contiguous chunk of the by-major grid
  const int nwg = gridDim.x * gridDim.y;
  const int flat = blockIdx.y * gridDim.x + blockIdx.x;
  const int swz = (flat & 7) * (nwg >> 3) + (flat >> 3);
  const int m0 = (swz % gridDim.x) * 128, n0 = (swz / gridDim.x) * BN;

  const int lr = lane >> 2;
  const int lc = (lane & 3) * 8;
  const unsigned short* gA0 = A + (size_t)(m0 + wave * 16 + lr) * K + lc;
  const unsigned short* gA1 = A + (size_t)(m0 + 64 + wave * 16 + lr) * K + lc;
  unsigned short* lA0 = lA + (wave * 16) * 32;
  unsigned short* lA1 = lA + (64 + wave * 16) * 32;
  const unsigned short* gB0 = B + (size_t)(n0 + wave * 16 + lr) * K + lc;
  const unsigned short* gB1 = B + (size_t)(n0 + 64 + wave * 16 + lr) * K + lc;
  unsigned short* lB0 = lB + (wave * 16) * 32;
  unsigned short* lB1 = lB + (64 + wave * 16) * 32;

  f32x4 acc[4][NI];
#pragma unroll
  for (int i = 0; i < 4; i++)
#pragma unroll
    for (int j = 0; j < NI; j++) acc[i][j] = f32x4{0.f, 0.f, 0.f, 0.f};

  for (int k0 = 0; k0 < K; k0 += 32) {
    gl2lds16(gA0, lA0);
    gl2lds16(gA1, lA1);
    gl2lds16(gB0, lB0);
    if constexpr (BN == 128) gl2lds16(gB1, lB1);
    gA0 += 32; gA1 += 32; gB0 += 32;
    if constexpr (BN == 128) gB1 += 32;
    __syncthreads();
    bf16x8 af[4], bfr[NI];
#pragma unroll
    for (int mi = 0; mi < 4; mi++)
      af[mi] = *(const bf16x8*)&lA[(wm * 64 + mi * 16 + r16) * 32 + q4 * 8];
#pragma unroll
    for (int ni = 0; ni < NI; ni++)
      bfr[ni] = *(const bf16x8*)&lB[(wn * (BN / 2) + ni * 16 + r16) * 32 + q4 * 8];
#pragma unroll
    for (int mi = 0; mi < 4; mi++)
#pragma unroll
      for (int ni = 0; ni < NI; ni++)
        acc[mi][ni] = mfma16(af[mi], bfr[ni], acc[mi][ni]);
    __syncthreads();
  }
#pragma unroll
  for (int mi = 0; mi < 4; mi++)
#pragma unroll
    for (int ni = 0; ni < NI; ni++) {
      int col = n0 + wn * (BN / 2) + ni * 16 + r16;
#pragma unroll
      for (int rr = 0; rr < 4; rr++) {
        int row = m0 + wm * 64 + mi * 16 + q4 * 4 + rr;
        size_t idx = (size_t)row * N + col;
        float v = acc[mi][ni][rr];
        if constexpr (EPI == 0) {
          ((unsigned short*)C)[idx] = f2bf(v);
        } else if constexpr (EPI == 1) {
          ((unsigned short*)C)[idx] = f2bf(v + ((const float*)res)[idx]);
        } else {
          ((float*)C)[idx] = v + bf2f(((const unsigned short*)res)[idx]);
        }
      }
    }
}

// ---------------- Fused gate/up GEMM + silu*mul -> bf16 (BM=128, BN=64) ----------------
// R3: XCD-aware block remap (nwg = 16*88 = 1408, %8 == 0).
__global__ __launch_bounds__(256) void gemm_gateup(const unsigned short* __restrict__ A,
                                                   const unsigned short* __restrict__ Bg,
                                                   const unsigned short* __restrict__ Bu,
                                                   unsigned short* __restrict__ act) {
  __shared__ __align__(16) unsigned short lA[128 * 32];
  __shared__ __align__(16) unsigned short lG[64 * 32];
  __shared__ __align__(16) unsigned short lU[64 * 32];
  const int tid = threadIdx.x, lane = tid & 63, wave = tid >> 6;
  const int r16 = lane & 15, q4 = lane >> 4;
  const int wm = wave >> 1, wn = wave & 1;
  const int nwg = gridDim.x * gridDim.y;
  const int flat = blockIdx.y * gridDim.x + blockIdx.x;
  const int swz = (flat & 7) * (nwg >> 3) + (flat >> 3);
  const int m0 = (swz % gridDim.x) * 128, n0 = (swz / gridDim.x) * 64;
  const int K = D_MODEL;

  const int lr = lane >> 2, lc = (lane & 3) * 8;
  const unsigned short* gA0 = A + (size_t)(m0 + wave * 16 + lr) * K + lc;
  const unsigned short* gA1 = A + (size_t)(m0 + 64 + wave * 16 + lr) * K + lc;
  unsigned short* lA0 = lA + (wave * 16) * 32;
  unsigned short* lA1 = lA + (64 + wave * 16) * 32;
  const unsigned short* gG0 = Bg + (size_t)(n0 + wave * 16 + lr) * K + lc;
  const unsigned short* gU0 = Bu + (size_t)(n0 + wave * 16 + lr) * K + lc;
  unsigned short* lG0 = lG + (wave * 16) * 32;
  unsigned short* lU0 = lU + (wave * 16) * 32;

  f32x4 ag[4][2], au[4][2];
#pragma unroll
  for (int i = 0; i < 4; i++)
#pragma unroll
    for (int j = 0; j < 2; j++) { ag[i][j] = f32x4{0.f,0.f,0.f,0.f}; au[i][j] = f32x4{0.f,0.f,0.f,0.f}; }

  for (int k0 = 0; k0 < K; k0 += 32) {
    gl2lds16(gA0, lA0);
    gl2lds16(gA1, lA1);
    gl2lds16(gG0, lG0);
    gl2lds16(gU0, lU0);
    gA0 += 32; gA1 += 32; gG0 += 32; gU0 += 32;
    __syncthreads();
    bf16x8 af[4], bg2[2], bu2[2];
#pragma unroll
    for (int mi = 0; mi < 4; mi++)
      af[mi] = *(const bf16x8*)&lA[(wm * 64 + mi * 16 + r16) * 32 + q4 * 8];
#pragma unroll
    for (int ni = 0; ni < 2; ni++) {
      int r = (wn * 32 + ni * 16 + r16) * 32 + q4 * 8;
      bg2[ni] = *(const bf16x8*)&lG[r];
      bu2[ni] = *(const bf16x8*)&lU[r];
    }
#pragma unroll
    for (int mi = 0; mi < 4; mi++)
#pragma unroll
      for (int ni = 0; ni < 2; ni++) {
        ag[mi][ni] = mfma16(af[mi], bg2[ni], ag[mi][ni]);
        au[mi][ni] = mfma16(af[mi], bu2[ni], au[mi][ni]);
      }
    __syncthreads();
  }
#pragma unroll
  for (int mi = 0; mi < 4; mi++)
#pragma unroll
    for (int ni = 0; ni < 2; ni++) {
      int col = n0 + wn * 32 + ni * 16 + r16;
#pragma unroll
      for (int rr = 0; rr < 4; rr++) {
        int row = m0 + wm * 64 + mi * 16 + q4 * 4 + rr;
        float g = ag[mi][ni][rr], u = au[mi][ni][rr];
        float sil = g / (1.0f + __expf(-g));
        act[(size_t)row * FFDIM + col] = f2bf(sil * u);
      }
    }
}

// -------- RoPE for keys: fp32 cache + bf16 new (GQA repeat) -> keys_bf[H][KV][HD] --------
__global__ __launch_bounds__(256) void rope_k_k(const float* __restrict__ k_cache,
                                                const unsigned short* __restrict__ qkv,
                                                unsigned short* __restrict__ keys_bf) {
  int idx = blockIdx.x * 256 + threadIdx.x;        // [h][j][d]
  int d = idx & 127, j = (idx >> 7) & 4095, h = idx >> 19;
  int dd = d & 63;
  float inv = __expf(-(float)dd * LN10K_64);
  float ang = (float)j * inv;
  float c = cosf(ang), sn = sinf(ang);
  float x, xr;
  if (j < PREFIX) {
    const float* row = k_cache + ((size_t)h * PREFIX + j) * HDIM;
    x = row[d];
    xr = (d < 64) ? -row[d + 64] : row[d - 64];
  } else {
    const unsigned short* row = qkv + (size_t)(j - PREFIX) * 4096 + 2048 + (h >> 1) * HDIM;
    x = bf2f(row[d]);
    xr = (d < 64) ? -bf2f(row[d + 64]) : bf2f(row[d - 64]);
  }
  keys_bf[idx] = f2bf(x * c + xr * sn);
}

// -------- V transpose: fp32 cache + bf16 new -> vals_t[H][HD][KV] bf16 --------
__global__ __launch_bounds__(256) void vtrans_k(const float* __restrict__ v_cache,
                                                const unsigned short* __restrict__ qkv,
                                                unsigned short* __restrict__ vals_t) {
  __shared__ float tile[32][33];
  const int h = blockIdx.z, j0 = blockIdx.x * 32, d0 = blockIdx.y * 32;
  const int t = threadIdx.x;
#pragma unroll
  for (int i = 0; i < 4; i++) {
    int e = i * 256 + t;
    int jj = e >> 5, dd = e & 31;
    float v;
    if (j0 < PREFIX)
      v = v_cache[((size_t)h * PREFIX + j0 + jj) * HDIM + d0 + dd];
    else
      v = bf2f(qkv[(size_t)(j0 - PREFIX + jj) * 4096 + 3072 + (h >> 1) * HDIM + d0 + dd]);
    tile[jj][dd] = v;
  }
  __syncthreads();
#pragma unroll
  for (int i = 0; i < 4; i++) {
    int e = i * 256 + t;
    int dd = e >> 5, jj = e & 31;
    vals_t[((size_t)h * HDIM + d0 + dd) * KVLEN + j0 + jj] = f2bf(tile[jj][dd]);
  }
}

// ---------------- Split-KV flash attention v2 ----------------
// 1-D grid 1536 = 8 XCDs x 192 blocks. R4 balanced mapping: XCD x owns
// heads {2x, 2x+1} for ALL segs: per XCD = 2x(seg0 512 + seg1 512 + seg2
// 144) = 2336 tiles (exactly total/8). Footprint = 2 heads full K+V = 4MB.
// Long seg0/seg1 blocks dispatch first; short seg2 blocks form the tail.
// Key-interleaved K staging (LDS row rho holds key (rho&15)*4 + (rho>>4));
// constant-max exp2 softmax; fused Q-RoPE.
// LDS layouts (XOR-swizzled, slot ^= row&7, 16B slots):
//   lK [64 rho][128 dims]  256B rows — pre-swizzled global source
//   lV [128 dim][64 keys]  128B rows — pre-swizzled global source
//   lP [wave][16 q][64 keys] 128B rows — swizzled ds_write_b64 / ds_read_b128
__global__ __launch_bounds__(256) void attn_k(const unsigned short* __restrict__ qkv,
                                              const unsigned short* __restrict__ keys,
                                              const unsigned short* __restrict__ valst,
                                              const int* __restrict__ chunkp,
                                              unsigned short* __restrict__ pO,
                                              float* __restrict__ pl) {
  __shared__ __align__(16) unsigned short lK[64 * 128];    // [rho][dims], swizzled
  __shared__ __align__(16) unsigned short lV[128 * 64];    // [dim][keys], swizzled
  __shared__ __align__(16) unsigned short lP[4][16 * 64];  // [wave][q][keys], swizzled
  // ---- balanced XCD-aware work mapping (grid = 1536 1-D) ----
  const int flat = blockIdx.x;
  const int xcd = flat & 7, ii = flat >> 3;        // ii in [0,192)
  const int p = ii >> 5;                           // 0..5 within XCD
  const int seg = p >> 1;                          // 0,0,1,1,2,2
  const int h = xcd * 2 + (p & 1);                 // heads {2x, 2x+1}
  const int q0 = (ii & 31) * 64;
  const int tid = threadIdx.x, wave = tid >> 6, lane = tid & 63;
  const int r16 = lane & 15, q4 = lane >> 4;
  const int chunk = chunkp[0];
  const int sw = (r16 & 7) << 4;                 // read-side XOR swizzle

  // ---- Q load + RoPE (A-frag row = q0+wave*16+r16, dims ks*32+q4*8..+7) ----
  const int qrow = q0 + wave * 16 + r16;
  const unsigned short* qr = qkv + (size_t)qrow * 4096 + h * HDIM;
  float qx[4][8];
#pragma unroll
  for (int ks = 0; ks < 4; ks++) {
    bf16x8 raw = *(const bf16x8*)(qr + ks * 32 + q4 * 8);
#pragma unroll
    for (int j = 0; j < 8; j++) qx[ks][j] = bf2f((unsigned short)raw[j]);
  }
  const float pos = (float)(PREFIX + qrow);
  bf16x8 qf[4];
#pragma unroll
  for (int ks = 0; ks < 4; ks++)
#pragma unroll
    for (int j = 0; j < 8; j++) {
      int d = ks * 32 + q4 * 8 + j;
      float inv = __expf(-(float)(d & 63) * LN10K_64);
      float ang = pos * inv;
      float c = cosf(ang), sn = sinf(ang);
      float other = qx[ks ^ 2][j];
      float rot = (ks < 2) ? -other : other;
      qf[ks][j] = (short)f2bf(qx[ks][j] * c + rot * sn);
    }

  float lrow[4] = {0.f, 0.f, 0.f, 0.f};
  f32x4 oacc[8];
#pragma unroll
  for (int ni = 0; ni < 8; ni++) oacc[ni] = f32x4{0.f, 0.f, 0.f, 0.f};

  const int irow_base = q0 + wave * 16 + q4 * 4;   // C-layout rows
  const unsigned short* Kh = keys + (size_t)h * KVLEN * HDIM;
  const unsigned short* Vh = valst + (size_t)h * HDIM * KVLEN;

  // ---- staging bases (linear LDS dest; XOR-swizzled global source) ----
  const int krow = wave * 4 + (lane >> 4);                       // rho & 15
  const unsigned short* kSrc = Kh + (size_t)(krow * 4) * HDIM
                               + (((lane & 15) ^ (krow & 7)) * 8);
  unsigned short* kDst = lK + (wave * 4) * 128;
  const int vrow = wave * 8 + (lane >> 3);
  const unsigned short* vSrc = Vh + (size_t)vrow * KVLEN
                               + (((lane & 7) ^ ((lane >> 3) & 7)) * 8);
  unsigned short* vDst = lV + (wave * 8) * 64;

  int kt0, ktN;
  if (seg == 0)      { kt0 = 0;    ktN = 1024; }
  else if (seg == 1) { kt0 = 1024; ktN = 2048; }
  else { int cs = (q0 / chunk) * chunk; kt0 = PREFIX + cs; ktN = PREFIX + q0 + 64; }

  for (int kt = kt0; kt < ktN; kt += 64) {
    const bool domask = (seg == 2) && (kt - PREFIX + 64 > q0);
    // K stage: 4 rows (256B each) per wave per iteration
#pragma unroll
    for (int i = 0; i < 4; i++)
      gl2lds16(kSrc + (size_t)(kt + i) * HDIM, kDst + i * 16 * 128);
    // V stage: 8 rows (128B each) per wave per iteration
#pragma unroll
    for (int i = 0; i < 4; i++)
      gl2lds16(vSrc + (size_t)i * 32 * KVLEN + kt, vDst + i * 32 * 64);
    __syncthreads();
    // QK — kf row j*16+r16 (256B rows), dim bytes (ks*64+q4*16)^sw
    f32x4 s[4];
#pragma unroll
    for (int j = 0; j < 4; j++) s[j] = f32x4{0.f, 0.f, 0.f, 0.f};
#pragma unroll
    for (int ks = 0; ks < 4; ks++)
#pragma unroll
      for (int j = 0; j < 4; j++) {
        bf16x8 kf = *(const bf16x8*)((const char*)lK + (j * 16 + r16) * 256
                                     + ((ks * 64 + q4 * 16) ^ sw));
        s[j] = mfma16(qf[ks], kf, s[j]);
      }
    // constant-max softmax; lane's cols = keys kt + r16*4 + j
    const int klb = kt - PREFIX + r16 * 4;
#pragma unroll
    for (int rr = 0; rr < 4; rr++) {
      float e0 = fmaf(s[0][rr], SM_L2E, -MCONST);
      float e1 = fmaf(s[1][rr], SM_L2E, -MCONST);
      float e2 = fmaf(s[2][rr], SM_L2E, -MCONST);
      float e3 = fmaf(s[3][rr], SM_L2E, -MCONST);
      if (domask) {
        int irow = irow_base + rr;
        if (klb     > irow) e0 = -1e30f;
        if (klb + 1 > irow) e1 = -1e30f;
        if (klb + 2 > irow) e2 = -1e30f;
        if (klb + 3 > irow) e3 = -1e30f;
      }
      float p0 = exp2f(e0), p1 = exp2f(e1), p2 = exp2f(e2), p3 = exp2f(e3);
      lrow[rr] += (p0 + p1) + (p2 + p3);
      uint2 pk = make_uint2(pack2(p0, p1), pack2(p2, p3));
      int qrw = q4 * 4 + rr;                         // q-row within 16-tile
      *(uint2*)((char*)lP[wave] + qrw * 128 + ((r16 * 8) ^ ((qrw & 7) << 4))) = pk;
    }
    // PV (P exchange is intra-wave; DS ops are in-order per wave)
    bf16x8 pf0 = *(const bf16x8*)((const char*)lP[wave] + r16 * 128
                                  + ((q4 * 16) ^ sw));
    bf16x8 pf1 = *(const bf16x8*)((const char*)lP[wave] + r16 * 128
                                  + ((64 + q4 * 16) ^ sw));
#pragma unroll
    for (int ni = 0; ni < 8; ni++) {
      bf16x8 v0 = *(const bf16x8*)((const char*)lV + (ni * 16 + r16) * 128
                                   + ((q4 * 16) ^ sw));
      oacc[ni] = mfma16(pf0, v0, oacc[ni]);
      bf16x8 v1 = *(const bf16x8*)((const char*)lV + (ni * 16 + r16) * 128
                                   + ((64 + q4 * 16) ^ sw));
      oacc[ni] = mfma16(pf1, v1, oacc[ni]);
    }
    __syncthreads();   // protect lK/lV before next tile's staging
  }

  // deferred cross-lane l reduction (over the 16 r16 lanes)
#pragma unroll
  for (int rr = 0; rr < 4; rr++) {
    lrow[rr] += __shfl_xor(lrow[rr], 1);
    lrow[rr] += __shfl_xor(lrow[rr], 2);
    lrow[rr] += __shfl_xor(lrow[rr], 4);
    lrow[rr] += __shfl_xor(lrow[rr], 8);
  }
  const size_t base = (size_t)(seg * NH + h) * S_LEN;
#pragma unroll
  for (int ni = 0; ni < 8; ni++)
#pragma unroll
    for (int rr = 0; rr < 4; rr++)
      pO[(base + irow_base + rr) * HDIM + ni * 16 + r16] = f2bf(oacc[ni][rr]);
  if (r16 == 0) {
#pragma unroll
    for (int rr = 0; rr < 4; rr++) pl[base + irow_base + rr] = lrow[rr];
  }
}

// ---------------- combine 3 split-KV partials (same const max) ----------------
__global__ __launch_bounds__(256) void attn_combine(const unsigned short* __restrict__ pO,
                                                    const float* __restrict__ pl,
                                                    unsigned short* __restrict__ out) {
  int idx = blockIdx.x * 256 + threadIdx.x;        // [h][q][d]
  int d = idx & 127, hq = idx >> 7;                // hq = h*2048+q
  const int R = NH * S_LEN;
  float L = pl[hq] + pl[hq + R] + pl[hq + 2 * R];
  float o = bf2f(pO[(size_t)hq * HDIM + d])
          + bf2f(pO[(size_t)(hq + R) * HDIM + d])
          + bf2f(pO[(size_t)(hq + 2 * R) * HDIM + d]);
  int h = hq >> 11, q = hq & 2047;
  out[(size_t)q * D_MODEL + h * HDIM + d] = f2bf(o / L);
}

// ---------------- host launcher ----------------
extern "C" void kernel_launch(void* const* d_in, const int* in_sizes, int n_in,
                              void* d_out, int out_size, void* d_ws, size_t ws_size,
                              hipStream_t stream) {
  (void)in_sizes; (void)n_in; (void)out_size;
  const float* hidden  = (const float*)d_in[0];
  const float* k_cache = (const float*)d_in[1];
  const float* v_cache = (const float*)d_in[2];
  const float* q_w     = (const float*)d_in[3];
  const float* k_w     = (const float*)d_in[4];
  const float* v_w     = (const float*)d_in[5];
  const float* o_w     = (const float*)d_in[6];
  const float* gate_w  = (const float*)d_in[7];
  const float* up_w    = (const float*)d_in[8];
  const float* down_w  = (const float*)d_in[9];
  const float* ln1     = (const float*)d_in[10];
  const float* ln2     = (const float*)d_in[11];
  const int*   chunkp  = (const int*)d_in[12];

  if (ws_size < 92274688) return;  // 88 MB scratch
  char* ws = (char*)d_ws;
  const size_t MB = 1048576;
  // liveness-packed map (phases: conv/qkv -> rope/attn -> combine/oproj -> mlp)
  unsigned short* qkvpre = (unsigned short*)(ws + 0 * MB);   // 16 MB, live C..F
  unsigned short* keysbf = (unsigned short*)(ws + 16 * MB);  // 16 MB, live D..F
  unsigned short* valst  = (unsigned short*)(ws + 32 * MB);  // 16 MB, live E..F
  unsigned short* pO     = (unsigned short*)(ws + 48 * MB);  // 24 MB, live F..G
  float*          pl     = (float*)(ws + 88 * MB - 393216);  // 384 KB, live F..G
  unsigned short* WQKV   = (unsigned short*)(ws + 72 * MB);  // 16 MB, live B..C
  unsigned short* hn     = (unsigned short*)(ws + 48 * MB);  //  8 MB, live A..C (pre-pO)
  unsigned short* attnbf = (unsigned short*)(ws + 72 * MB);  //  8 MB, live G..I (WQKV dead)
  unsigned short* WO     = (unsigned short*)(ws + 80 * MB);  //  8 MB, live H..I
  unsigned short* h2     = (unsigned short*)(ws + 48 * MB);  //  8 MB, live I..N (pO dead)
  unsigned short* h2n    = (unsigned short*)(ws + 56 * MB);  //  8 MB, live J..L
  unsigned short* WG     = (unsigned short*)(ws + 0 * MB);   // 22 MB, live K..L
  unsigned short* WU     = (unsigned short*)(ws + 22 * MB);  // 22 MB, live K..L
  unsigned short* act    = (unsigned short*)(ws + 64 * MB);  // 22 MB, live L..N
  unsigned short* WD     = (unsigned short*)(ws + 0 * MB);   // 22 MB, live M..N (WG dead)
  float* out = (float*)d_out;

  rmsnorm_k<false><<<S_LEN, 256, 0, stream>>>(hidden, ln1, hn);                    // A
  conv3_k<<<4096, 256, 0, stream>>>(q_w, k_w, v_w, WQKV);                          // B
  gemm_bf<128, 0><<<dim3(16, 32), 256, 0, stream>>>(hn, WQKV, nullptr, qkvpre,     // C
                                                    S_LEN, 4096, D_MODEL);
  rope_k_k<<<(NH * KVLEN * HDIM) / 256, 256, 0, stream>>>(k_cache, qkvpre, keysbf);// D
  vtrans_k<<<dim3(KVLEN / 32, HDIM / 32, NH), 256, 0, stream>>>(v_cache, qkvpre, valst); // E
  attn_k<<<1536, 256, 0, stream>>>(qkvpre, keysbf, valst, chunkp, pO, pl);         // F
  attn_combine<<<(NH * S_LEN * HDIM) / 256, 256, 0, stream>>>(pO, pl, attnbf);     // G
  convw_k<<<2048, 256, 0, stream>>>(o_w, WO);                                      // H
  gemm_bf<64, 1><<<dim3(16, 32), 256, 0, stream>>>(attnbf, WO, hidden, h2,         // I
                                                   S_LEN, D_MODEL, D_MODEL);
  rmsnorm_k<true><<<S_LEN, 256, 0, stream>>>(h2, ln2, h2n);                        // J
  conv2_k<<<11264, 256, 0, stream>>>(gate_w, up_w, WG, WU);                        // K
  gemm_gateup<<<dim3(16, FFDIM / 64), 256, 0, stream>>>(h2n, WG, WU, act);         // L
  convw_k<<<5632, 256, 0, stream>>>(down_w, WD);                                   // M
  gemm_bf<64, 2><<<dim3(16, 32), 256, 0, stream>>>(act, WD, h2, out,               // N
                                                   S_LEN, D_MODEL, FFDIM);
}